// Round 5
// baseline (405.784 us; speedup 1.0000x reference)
//
#include <hip/hip_runtime.h>
#include <hip/hip_bf16.h>
#include <math.h>

#define S_LEN 2048
#define C_DIM 1024
#define NH    16
#define HD    64
#define TOPK  128

typedef __attribute__((ext_vector_type(8))) short s16x8;
typedef __attribute__((ext_vector_type(4))) float f32x4;

#define KSCALE 250000.0f
#define KINV   (1.0f / 250000.0f)
#define KOFF   0.13f
#define SUW    2056   // su row stride (u16): 4112B/row -> 4-bank shift/row

// ---------------- f32 -> bf16 convert ----------------
__global__ void cvt_f32_bf16(const float* __restrict__ in, __hip_bfloat16* __restrict__ out, int n) {
    int idx = (blockIdx.x * blockDim.x + threadIdx.x) * 4;
    if (idx + 3 < n) {
        float4 v = *(const float4*)(in + idx);
        out[idx + 0] = __float2bfloat16(v.x);
        out[idx + 1] = __float2bfloat16(v.y);
        out[idx + 2] = __float2bfloat16(v.z);
        out[idx + 3] = __float2bfloat16(v.w);
    }
}

// ---------------- GEMM (m97 structure): C[M][N] = A[M][K] * B[N][K]^T ----------------
typedef const __attribute__((address_space(1))) unsigned int* gp32;
typedef __attribute__((address_space(3))) unsigned int* lp32;

__global__ __launch_bounds__(256) void gemm_bt(const __hip_bfloat16* __restrict__ A,
                                               const __hip_bfloat16* __restrict__ B,
                                               float* __restrict__ C,
                                               int M, int N, int K)
{
    __shared__ short As[128 * 32];
    __shared__ short Bs[128 * 32];
    const int bm = blockIdx.y * 128;
    const int bn = blockIdx.x * 128;
    const int tid = threadIdx.x;
    const int lane = tid & 63;
    const int wave = tid >> 6;
    const int wm = (wave >> 1) * 64;
    const int wn = (wave & 1) * 64;

    f32x4 acc[4][4] = {};

    const int srow = tid >> 2;
    const int scol = (tid & 3) * 8;
    const int fr = lane & 15;
    const int fk = (lane >> 4) * 8;

    const short* Ab = (const short*)A;
    const short* Bb = (const short*)B;

    for (int k0 = 0; k0 < K; k0 += 32) {
        __syncthreads();
        __builtin_amdgcn_global_load_lds((gp32)(Ab + (size_t)(bm + srow) * K + k0 + scol),
                                         (lp32)((char*)As + tid * 16), 16, 0, 0);
        __builtin_amdgcn_global_load_lds((gp32)(Ab + (size_t)(bm + 64 + srow) * K + k0 + scol),
                                         (lp32)((char*)As + 4096 + tid * 16), 16, 0, 0);
        __builtin_amdgcn_global_load_lds((gp32)(Bb + (size_t)(bn + srow) * K + k0 + scol),
                                         (lp32)((char*)Bs + tid * 16), 16, 0, 0);
        __builtin_amdgcn_global_load_lds((gp32)(Bb + (size_t)(bn + 64 + srow) * K + k0 + scol),
                                         (lp32)((char*)Bs + 4096 + tid * 16), 16, 0, 0);
        __syncthreads();

        s16x8 af[4], bfr[4];
        #pragma unroll
        for (int m = 0; m < 4; ++m) af[m]  = *(const s16x8*)&As[(wm + m * 16 + fr) * 32 + fk];
        #pragma unroll
        for (int n = 0; n < 4; ++n) bfr[n] = *(const s16x8*)&Bs[(wn + n * 16 + fr) * 32 + fk];
        #pragma unroll
        for (int m = 0; m < 4; ++m)
            #pragma unroll
            for (int n = 0; n < 4; ++n)
                acc[m][n] = __builtin_amdgcn_mfma_f32_16x16x32_bf16(af[m], bfr[n], acc[m][n], 0, 0, 0);
    }

    const int cr = (lane >> 4) * 4;
    const int cc = lane & 15;
    #pragma unroll
    for (int m = 0; m < 4; ++m)
        #pragma unroll
        for (int n = 0; n < 4; ++n)
            #pragma unroll
            for (int j = 0; j < 4; ++j) {
                int row = bm + wm + m * 16 + cr + j;
                int col = bn + wn + n * 16 + cc;
                C[(size_t)row * N + col] = acc[m][n][j];
            }
}

// ---------------- RoPE + L2-normalize + head split (bf16 hi/lo q,k; bf16 v) ----------
__global__ __launch_bounds__(256) void rope_norm(const float* __restrict__ qkv,
                                                 __hip_bfloat16* __restrict__ qhi,
                                                 __hip_bfloat16* __restrict__ qlo,
                                                 __hip_bfloat16* __restrict__ khi,
                                                 __hip_bfloat16* __restrict__ klo,
                                                 __hip_bfloat16* __restrict__ vh)
{
    const int gw = blockIdx.x * 4 + (threadIdx.x >> 6);
    const int lane = threadIdx.x & 63;
    const int h = gw >> 11;
    const int s = gw & 2047;
    const float* base = qkv + (size_t)s * (3 * C_DIM);
    float qx = base[h * HD + lane];
    float kx = base[C_DIM + h * HD + lane];
    float vx = base[2 * C_DIM + h * HD + lane];

    const int i = lane >> 1;
    const float invf = expf(-(float)(2 * i) * (9.210340371976184f / 64.f));
    const float ang = (float)s * invf;
    float sn, cs;
    sincosf(ang, &sn, &cs);
    float qp = __shfl_xor(qx, 1);
    float kp = __shfl_xor(kx, 1);
    const float sgn = (lane & 1) ? 1.f : -1.f;
    float qr = qx * cs + sgn * qp * sn;
    float kr = kx * cs + sgn * kp * sn;

    float s2q = qr * qr, s2k = kr * kr;
    #pragma unroll
    for (int off = 32; off > 0; off >>= 1) {
        s2q += __shfl_xor(s2q, off);
        s2k += __shfl_xor(s2k, off);
    }
    qr = qr / fmaxf(sqrtf(s2q), 1e-12f);
    kr = kr / fmaxf(sqrtf(s2k), 1e-12f);

    size_t o = ((size_t)h * S_LEN + s) * HD + lane;
    __hip_bfloat16 qh_ = __float2bfloat16(qr);
    __hip_bfloat16 kh_ = __float2bfloat16(kr);
    qhi[o] = qh_; qlo[o] = __float2bfloat16(qr - __bfloat162float(qh_));
    khi[o] = kh_; klo[o] = __float2bfloat16(kr - __bfloat162float(kh_));
    vh[o] = __float2bfloat16(vx);
}

// ---------------- wave helpers ----------------
__device__ __forceinline__ unsigned wave_prefix_incl(unsigned v, int lane) {
    #pragma unroll
    for (int off = 1; off < 64; off <<= 1) {
        unsigned t = __shfl_up(v, off);
        v += (lane >= off) ? t : 0u;
    }
    return v;
}

// bins at indices lane*4 + {0..3}; find threshold byte B (descending)
__device__ __forceinline__ void find_byte4(unsigned bb0, unsigned bb1, unsigned bb2, unsigned bb3,
                                           int need, int lane, int& B, int& needRem, int& eqc)
{
    unsigned sl = bb0 + bb1 + bb2 + bb3;
    unsigned suf = sl;
    #pragma unroll
    for (int off = 1; off < 64; off <<= 1) {
        unsigned t = __shfl_down(suf, off);
        suf += (lane + off < 64) ? t : 0u;
    }
    bool qual = (suf >= (unsigned)need) && (suf - sl < (unsigned)need);
    unsigned long long mask = __ballot(qual);
    int src = (int)__builtin_ctzll(mask);

    unsigned cum = suf - sl;
    int myB = 0; unsigned myAbove = 0, myEq = 0;
    if (cum + bb3 >= (unsigned)need) { myB = lane * 4 + 3; myAbove = cum; myEq = bb3; }
    else {
        cum += bb3;
        if (cum + bb2 >= (unsigned)need) { myB = lane * 4 + 2; myAbove = cum; myEq = bb2; }
        else {
            cum += bb2;
            if (cum + bb1 >= (unsigned)need) { myB = lane * 4 + 1; myAbove = cum; myEq = bb1; }
            else {
                cum += bb1;
                if (cum + bb0 >= (unsigned)need) { myB = lane * 4 + 0; myAbove = cum; myEq = bb0; }
            }
        }
    }
    B = __shfl(myB, src);
    needRem = need - (int)__shfl((int)myAbove, src);
    eqc = (int)__shfl((int)myEq, src);
}

// ---------------- attention v4: block = (8 q-rows, 1 head), 8 waves, 1 row/wave ------
// hist packed 2 bins/u32; pass-1 fused into score phase; 4 blocks/CU target.
__global__ __launch_bounds__(512, 8) void attn4(const __hip_bfloat16* __restrict__ qhi,
                                                const __hip_bfloat16* __restrict__ qlo,
                                                const __hip_bfloat16* __restrict__ khi,
                                                const __hip_bfloat16* __restrict__ klo,
                                                const __hip_bfloat16* __restrict__ vhb,
                                                __hip_bfloat16* __restrict__ yb)
{
    __shared__ unsigned short su[8][SUW];     // 32.9 KB quantized keys (0 = masked)
    __shared__ unsigned hist[8][128];         // 4 KB: 256 bins packed 2/u32, per row
    __shared__ unsigned short klist[8][TOPK]; // 2 KB

    const int h = blockIdx.x;                 // grid (NH, S/8): head-major -> per-XCD L2 locality
    const int q0 = blockIdx.y * 8;
    const int tid = threadIdx.x, lane = tid & 63, wv = tid >> 6;
    const int ntiles = (q0 + 8 + 63) >> 6;
    const int SB = ntiles * 64;
    const size_t hb = (size_t)h * S_LEN;

    // zero packed hist (8*128 = 1024 words), then barrier before any atomic
    ((unsigned*)hist)[tid] = 0u;
    ((unsigned*)hist)[tid + 512] = 0u;

    // ---- Q fragments: rows q0..q0+7 duplicated across fr 0-7 / 8-15 ----
    const int fr = lane & 15;
    const int ak = (lane >> 4) * 8;
    const short* qp_h = (const short*)qhi + (hb + q0 + (fr & 7)) * HD;
    const short* qp_l = (const short*)qlo + (hb + q0 + (fr & 7)) * HD;
    s16x8 qa_h0 = *(const s16x8*)(qp_h + ak);
    s16x8 qa_h1 = *(const s16x8*)(qp_h + ak + 32);
    s16x8 qa_l0 = *(const s16x8*)(qp_l + ak);
    s16x8 qa_l1 = *(const s16x8*)(qp_l + ak + 32);
    __syncthreads();

    // ---- scores via MFMA (split-bf16) + quantize + fused hi-byte histogram ----
    for (int t = wv; t < ntiles; t += 8) {
        const int k0 = t * 64;
        #pragma unroll
        for (int cb = 0; cb < 4; ++cb) {
            const int key = k0 + cb * 16 + fr;
            const short* kh_ = (const short*)khi + (hb + key) * HD;
            const short* kl_ = (const short*)klo + (hb + key) * HD;
            s16x8 b_h0 = *(const s16x8*)(kh_ + ak);
            s16x8 b_h1 = *(const s16x8*)(kh_ + ak + 32);
            s16x8 b_l0 = *(const s16x8*)(kl_ + ak);
            s16x8 b_l1 = *(const s16x8*)(kl_ + ak + 32);
            f32x4 acc = {};
            acc = __builtin_amdgcn_mfma_f32_16x16x32_bf16(qa_h0, b_h0, acc, 0, 0, 0);
            acc = __builtin_amdgcn_mfma_f32_16x16x32_bf16(qa_h1, b_h1, acc, 0, 0, 0);
            acc = __builtin_amdgcn_mfma_f32_16x16x32_bf16(qa_h0, b_l0, acc, 0, 0, 0);
            acc = __builtin_amdgcn_mfma_f32_16x16x32_bf16(qa_h1, b_l1, acc, 0, 0, 0);
            acc = __builtin_amdgcn_mfma_f32_16x16x32_bf16(qa_l0, b_h0, acc, 0, 0, 0);
            acc = __builtin_amdgcn_mfma_f32_16x16x32_bf16(qa_l1, b_h1, acc, 0, 0, 0);
            #pragma unroll
            for (int j = 0; j < 4; ++j) {
                const int rowD = (lane >> 4) * 4 + j;
                if (rowD < 8) {
                    float s = acc[j] * 0.125f;
                    int ku = 0;
                    if (key <= q0 + rowD) {
                        ku = 1 + (int)((s + KOFF) * KSCALE);
                        ku = ku < 1 ? 1 : (ku > 65535 ? 65535 : ku);
                        const int hibin = ku >> 8;
                        atomicAdd(&hist[rowD][hibin >> 1], (hibin & 1) ? 0x10000u : 1u);
                    }
                    su[rowD][key] = (unsigned short)ku;
                }
            }
        }
    }
    __syncthreads();

    // ---- per-wave: row = wv ----
    const int nchT = (SB + 255) >> 8;
    const int row = wv;
    const int q = q0 + row;
    const int need = (q + 1 < TOPK) ? q + 1 : TOPK;

    if (q < TOPK) {
        for (int s = lane; s < need; s += 64) klist[row][s] = (unsigned short)s;
        for (int s = need + lane; s < TOPK; s += 64) klist[row][s] = 0;
    } else {
        // B1 from fused hi-byte histogram
        unsigned w0 = hist[row][lane * 2], w1 = hist[row][lane * 2 + 1];
        int B1, need2, eqc1;
        find_byte4(w0 & 0xffffu, w0 >> 16, w1 & 0xffffu, w1 >> 16, need, lane, B1, need2, eqc1);

        // zero own hist row, then lo-byte pass among hi==B1
        hist[row][lane * 2] = 0u; hist[row][lane * 2 + 1] = 0u;
        __asm__ volatile("s_waitcnt lgkmcnt(0)" ::: "memory");
        for (int c = 0; c < nchT; ++c) {
            const int base = (c << 8) + lane * 4;
            if (base < SB) {
                unsigned long long w8 = *(const unsigned long long*)&su[row][base];
                #pragma unroll
                for (int jj = 0; jj < 4; ++jj) {
                    unsigned kx = (unsigned)((w8 >> (16 * jj)) & 0xffffu);
                    if (kx && (kx >> 8) == (unsigned)B1) {
                        unsigned lob = kx & 255u;
                        atomicAdd(&hist[row][lob >> 1], (lob & 1) ? 0x10000u : 1u);
                    }
                }
            }
        }
        __asm__ volatile("s_waitcnt lgkmcnt(0)" ::: "memory");
        unsigned v0 = hist[row][lane * 2], v1 = hist[row][lane * 2 + 1];
        int B2, takeEq, eqc2;
        find_byte4(v0 & 0xffffu, v0 >> 16, v1 & 0xffffu, v1 >> 16, need2, lane, B2, takeEq, eqc2);

        const unsigned T = ((unsigned)B1 << 8) | (unsigned)B2;
        const int gtTot = need - takeEq;
        const bool tieEasy = (takeEq == eqc2);

        // compaction
        int gbase = 0, te = 0;
        for (int c = 0; c < nchT; ++c) {
            const int base = (c << 8) + lane * 4;
            const bool g = base < SB;
            unsigned long long w8 = g ? *(const unsigned long long*)&su[row][base] : 0ull;
            unsigned kk[4];
            kk[0] = (unsigned)(w8 & 0xffff); kk[1] = (unsigned)((w8 >> 16) & 0xffff);
            kk[2] = (unsigned)((w8 >> 32) & 0xffff); kk[3] = (unsigned)((w8 >> 48) & 0xffff);
            bool f0, f1, f2, f3;
            if (tieEasy) { f0 = kk[0] >= T; f1 = kk[1] >= T; f2 = kk[2] >= T; f3 = kk[3] >= T; }
            else         { f0 = kk[0] >  T; f1 = kk[1] >  T; f2 = kk[2] >  T; f3 = kk[3] >  T; }
            unsigned cl = (unsigned)f0 + f1 + f2 + f3;
            unsigned inc = wave_prefix_incl(cl, lane);
            int slot = gbase + (int)(inc - cl);
            if (f0) klist[row][slot++] = (unsigned short)(base + 0);
            if (f1) klist[row][slot++] = (unsigned short)(base + 1);
            if (f2) klist[row][slot++] = (unsigned short)(base + 2);
            if (f3) klist[row][slot++] = (unsigned short)(base + 3);
            gbase += (int)__shfl((int)inc, 63);
            if (!tieEasy) {
                #pragma unroll
                for (int j = 0; j < 4; ++j) {
                    bool tj = g && (kk[j] == T);
                    unsigned long long bal = __ballot(tj);
                    int r = te + (int)__popcll(bal & ((1ull << lane) - 1ull));
                    if (tj && r < takeEq) klist[row][gtTot + r] = (unsigned short)(base + j);
                    te += (int)__popcll(bal);
                }
            }
        }
    }
    __asm__ volatile("s_waitcnt lgkmcnt(0)" ::: "memory");

    // ---- PV: lane = (key-slot g=lane>>3, dim-slice d0=(lane&7)*8), bf16 V ----
    const int g = lane >> 3;
    const int d0 = (lane & 7) * 8;
    const short* vb = (const short*)vhb + hb * HD;
    float acc8[8] = {0.f, 0.f, 0.f, 0.f, 0.f, 0.f, 0.f, 0.f};
    float psum = 0.f;

    #pragma unroll
    for (int grp = 0; grp < 4; ++grp) {
        int kk[4]; float pp[4];
        #pragma unroll
        for (int b = 0; b < 4; ++b) {
            const int slot = (grp * 4 + b) * 8 + g;
            const int k = klist[row][slot];
            kk[b] = k;
            pp[b] = (slot < need) ? __expf(((float)su[row][k] - 0.5f) * KINV - KOFF) : 0.f;
        }
        s16x8 vv[4];
        #pragma unroll
        for (int b = 0; b < 4; ++b) vv[b] = *(const s16x8*)(vb + (size_t)kk[b] * HD + d0);
        #pragma unroll
        for (int b = 0; b < 4; ++b) {
            psum += pp[b];
            #pragma unroll
            for (int j = 0; j < 8; ++j) {
                unsigned short us = (unsigned short)vv[b][j];
                float vf = __bfloat162float(*reinterpret_cast<__hip_bfloat16*>(&us));
                acc8[j] += pp[b] * vf;
            }
        }
    }

    #pragma unroll
    for (int off = 8; off < 64; off <<= 1) {
        psum += __shfl_xor(psum, off);
        #pragma unroll
        for (int j = 0; j < 8; ++j) acc8[j] += __shfl_xor(acc8[j], off);
    }

    if (lane < 8) {
        const float inv = 1.0f / psum;
        s16x8 r;
        #pragma unroll
        for (int j = 0; j < 8; ++j) {
            __hip_bfloat16 bf = __float2bfloat16(acc8[j] * inv);
            r[j] = *reinterpret_cast<short*>(&bf);
        }
        *(s16x8*)((short*)yb + (size_t)q * C_DIM + h * HD + lane * 8) = r;
    }
}

// ---------------- launch ----------------
extern "C" void kernel_launch(void* const* d_in, const int* in_sizes, int n_in,
                              void* d_out, int out_size, void* d_ws, size_t ws_size,
                              hipStream_t stream)
{
    const float* x      = (const float*)d_in[0];
    const float* w_qkv  = (const float*)d_in[1];
    const float* w_proj = (const float*)d_in[2];
    float* out = (float*)d_out;

    char* ws = (char*)d_ws;
    size_t off = 0;
    auto alloc = [&](size_t bytes) -> void* {
        void* p = ws + off;
        off += (bytes + 255) & ~(size_t)255;
        return p;
    };
    __hip_bfloat16* xb  = (__hip_bfloat16*)alloc((size_t)S_LEN * C_DIM * 2);
    __hip_bfloat16* wqb = (__hip_bfloat16*)alloc((size_t)3 * C_DIM * C_DIM * 2);
    __hip_bfloat16* wpb = (__hip_bfloat16*)alloc((size_t)C_DIM * C_DIM * 2);
    float* qkvf = (float*)alloc((size_t)S_LEN * 3 * C_DIM * 4);
    __hip_bfloat16* qhi = (__hip_bfloat16*)alloc((size_t)NH * S_LEN * HD * 2);
    __hip_bfloat16* qlo = (__hip_bfloat16*)alloc((size_t)NH * S_LEN * HD * 2);
    __hip_bfloat16* khi = (__hip_bfloat16*)alloc((size_t)NH * S_LEN * HD * 2);
    __hip_bfloat16* klo = (__hip_bfloat16*)alloc((size_t)NH * S_LEN * HD * 2);
    __hip_bfloat16* vhb = (__hip_bfloat16*)alloc((size_t)NH * S_LEN * HD * 2);
    __hip_bfloat16* yb  = (__hip_bfloat16*)alloc((size_t)S_LEN * C_DIM * 2);

    int n1 = S_LEN * C_DIM, n2 = 3 * C_DIM * C_DIM, n3 = C_DIM * C_DIM;
    cvt_f32_bf16<<<n1 / 4 / 256, 256, 0, stream>>>(x, xb, n1);
    cvt_f32_bf16<<<n2 / 4 / 256, 256, 0, stream>>>(w_qkv, wqb, n2);
    cvt_f32_bf16<<<n3 / 4 / 256, 256, 0, stream>>>(w_proj, wpb, n3);

    gemm_bt<<<dim3(3 * C_DIM / 128, S_LEN / 128), 256, 0, stream>>>(xb, wqb, qkvf, S_LEN, 3 * C_DIM, C_DIM);

    rope_norm<<<NH * S_LEN / 4, 256, 0, stream>>>(qkvf, qhi, qlo, khi, klo, vhb);

    attn4<<<dim3(NH, S_LEN / 8), 512, 0, stream>>>(qhi, qlo, khi, klo, vhb, yb);

    gemm_bt<<<dim3(C_DIM / 128, S_LEN / 128), 256, 0, stream>>>(yb, wpb, out, S_LEN, C_DIM, C_DIM);
}

// Round 8
// 324.314 us; speedup vs baseline: 1.2512x; 1.2512x over previous
//
#include <hip/hip_runtime.h>
#include <hip/hip_bf16.h>
#include <math.h>

#define S_LEN 2048
#define C_DIM 1024
#define NH    16
#define HD    64
#define TOPK  128

typedef __attribute__((ext_vector_type(8))) short s16x8;
typedef __attribute__((ext_vector_type(4))) float f32x4;

#define KSCALE 250000.0f
#define KINV   (1.0f / 250000.0f)
#define KOFF   0.13f
#define SUW    2056   // su row stride (u16): 4112B/row -> 4-bank shift/row

// ---------------- f32 -> bf16 convert ----------------
__global__ void cvt_f32_bf16(const float* __restrict__ in, __hip_bfloat16* __restrict__ out, int n) {
    int idx = (blockIdx.x * blockDim.x + threadIdx.x) * 4;
    if (idx + 3 < n) {
        float4 v = *(const float4*)(in + idx);
        out[idx + 0] = __float2bfloat16(v.x);
        out[idx + 1] = __float2bfloat16(v.y);
        out[idx + 2] = __float2bfloat16(v.z);
        out[idx + 3] = __float2bfloat16(v.w);
    }
}

// ---------------- GEMM (m97 structure): C[M][N] = A[M][K] * B[N][K]^T ----------------
typedef const __attribute__((address_space(1))) unsigned int* gp32;
typedef __attribute__((address_space(3))) unsigned int* lp32;

__global__ __launch_bounds__(256) void gemm_bt(const __hip_bfloat16* __restrict__ A,
                                               const __hip_bfloat16* __restrict__ B,
                                               float* __restrict__ C,
                                               int M, int N, int K)
{
    __shared__ short As[128 * 32];
    __shared__ short Bs[128 * 32];
    const int bm = blockIdx.y * 128;
    const int bn = blockIdx.x * 128;
    const int tid = threadIdx.x;
    const int lane = tid & 63;
    const int wave = tid >> 6;
    const int wm = (wave >> 1) * 64;
    const int wn = (wave & 1) * 64;

    f32x4 acc[4][4] = {};

    const int srow = tid >> 2;
    const int scol = (tid & 3) * 8;
    const int fr = lane & 15;
    const int fk = (lane >> 4) * 8;

    const short* Ab = (const short*)A;
    const short* Bb = (const short*)B;

    for (int k0 = 0; k0 < K; k0 += 32) {
        __syncthreads();
        __builtin_amdgcn_global_load_lds((gp32)(Ab + (size_t)(bm + srow) * K + k0 + scol),
                                         (lp32)((char*)As + tid * 16), 16, 0, 0);
        __builtin_amdgcn_global_load_lds((gp32)(Ab + (size_t)(bm + 64 + srow) * K + k0 + scol),
                                         (lp32)((char*)As + 4096 + tid * 16), 16, 0, 0);
        __builtin_amdgcn_global_load_lds((gp32)(Bb + (size_t)(bn + srow) * K + k0 + scol),
                                         (lp32)((char*)Bs + tid * 16), 16, 0, 0);
        __builtin_amdgcn_global_load_lds((gp32)(Bb + (size_t)(bn + 64 + srow) * K + k0 + scol),
                                         (lp32)((char*)Bs + 4096 + tid * 16), 16, 0, 0);
        __syncthreads();

        s16x8 af[4], bfr[4];
        #pragma unroll
        for (int m = 0; m < 4; ++m) af[m]  = *(const s16x8*)&As[(wm + m * 16 + fr) * 32 + fk];
        #pragma unroll
        for (int n = 0; n < 4; ++n) bfr[n] = *(const s16x8*)&Bs[(wn + n * 16 + fr) * 32 + fk];
        #pragma unroll
        for (int m = 0; m < 4; ++m)
            #pragma unroll
            for (int n = 0; n < 4; ++n)
                acc[m][n] = __builtin_amdgcn_mfma_f32_16x16x32_bf16(af[m], bfr[n], acc[m][n], 0, 0, 0);
    }

    const int cr = (lane >> 4) * 4;
    const int cc = lane & 15;
    #pragma unroll
    for (int m = 0; m < 4; ++m)
        #pragma unroll
        for (int n = 0; n < 4; ++n)
            #pragma unroll
            for (int j = 0; j < 4; ++j) {
                int row = bm + wm + m * 16 + cr + j;
                int col = bn + wn + n * 16 + cc;
                C[(size_t)row * N + col] = acc[m][n][j];
            }
}

// ---------------- RoPE + L2-normalize + head split (bf16 hi/lo q,k; bf16 v) ----------
__global__ __launch_bounds__(256) void rope_norm(const float* __restrict__ qkv,
                                                 __hip_bfloat16* __restrict__ qhi,
                                                 __hip_bfloat16* __restrict__ qlo,
                                                 __hip_bfloat16* __restrict__ khi,
                                                 __hip_bfloat16* __restrict__ klo,
                                                 __hip_bfloat16* __restrict__ vh)
{
    const int gw = blockIdx.x * 4 + (threadIdx.x >> 6);
    const int lane = threadIdx.x & 63;
    const int h = gw >> 11;
    const int s = gw & 2047;
    const float* base = qkv + (size_t)s * (3 * C_DIM);
    float qx = base[h * HD + lane];
    float kx = base[C_DIM + h * HD + lane];
    float vx = base[2 * C_DIM + h * HD + lane];

    const int i = lane >> 1;
    const float invf = expf(-(float)(2 * i) * (9.210340371976184f / 64.f));
    const float ang = (float)s * invf;
    float sn, cs;
    sincosf(ang, &sn, &cs);
    float qp = __shfl_xor(qx, 1);
    float kp = __shfl_xor(kx, 1);
    const float sgn = (lane & 1) ? 1.f : -1.f;
    float qr = qx * cs + sgn * qp * sn;
    float kr = kx * cs + sgn * kp * sn;

    float s2q = qr * qr, s2k = kr * kr;
    #pragma unroll
    for (int off = 32; off > 0; off >>= 1) {
        s2q += __shfl_xor(s2q, off);
        s2k += __shfl_xor(s2k, off);
    }
    qr = qr / fmaxf(sqrtf(s2q), 1e-12f);
    kr = kr / fmaxf(sqrtf(s2k), 1e-12f);

    size_t o = ((size_t)h * S_LEN + s) * HD + lane;
    __hip_bfloat16 qh_ = __float2bfloat16(qr);
    __hip_bfloat16 kh_ = __float2bfloat16(kr);
    qhi[o] = qh_; qlo[o] = __float2bfloat16(qr - __bfloat162float(qh_));
    khi[o] = kh_; klo[o] = __float2bfloat16(kr - __bfloat162float(kh_));
    vh[o] = __float2bfloat16(vx);
}

// ---------------- wave helpers ----------------
__device__ __forceinline__ unsigned wave_prefix_incl(unsigned v, int lane) {
    #pragma unroll
    for (int off = 1; off < 64; off <<= 1) {
        unsigned t = __shfl_up(v, off);
        v += (lane >= off) ? t : 0u;
    }
    return v;
}

// bins at indices lane*4 + {0..3}; find threshold byte B (descending)
__device__ __forceinline__ void find_byte4(unsigned bb0, unsigned bb1, unsigned bb2, unsigned bb3,
                                           int need, int lane, int& B, int& needRem, int& eqc)
{
    unsigned sl = bb0 + bb1 + bb2 + bb3;
    unsigned suf = sl;
    #pragma unroll
    for (int off = 1; off < 64; off <<= 1) {
        unsigned t = __shfl_down(suf, off);
        suf += (lane + off < 64) ? t : 0u;
    }
    bool qual = (suf >= (unsigned)need) && (suf - sl < (unsigned)need);
    unsigned long long mask = __ballot(qual);
    int src = (int)__builtin_ctzll(mask);

    unsigned cum = suf - sl;
    int myB = 0; unsigned myAbove = 0, myEq = 0;
    if (cum + bb3 >= (unsigned)need) { myB = lane * 4 + 3; myAbove = cum; myEq = bb3; }
    else {
        cum += bb3;
        if (cum + bb2 >= (unsigned)need) { myB = lane * 4 + 2; myAbove = cum; myEq = bb2; }
        else {
            cum += bb2;
            if (cum + bb1 >= (unsigned)need) { myB = lane * 4 + 1; myAbove = cum; myEq = bb1; }
            else {
                cum += bb1;
                if (cum + bb0 >= (unsigned)need) { myB = lane * 4 + 0; myAbove = cum; myEq = bb0; }
            }
        }
    }
    B = __shfl(myB, src);
    needRem = need - (int)__shfl((int)myAbove, src);
    eqc = (int)__shfl((int)myEq, src);
}

// ---------------- attention v5: block = (8 q-rows, 1 head), 8 waves, 1 row/wave ------
// identical to v4 except __launch_bounds__(512,4): relax VGPR cap 64->128 to kill spill.
__global__ __launch_bounds__(512, 4) void attn5(const __hip_bfloat16* __restrict__ qhi,
                                                const __hip_bfloat16* __restrict__ qlo,
                                                const __hip_bfloat16* __restrict__ khi,
                                                const __hip_bfloat16* __restrict__ klo,
                                                const __hip_bfloat16* __restrict__ vhb,
                                                __hip_bfloat16* __restrict__ yb)
{
    __shared__ unsigned short su[8][SUW];     // 32.9 KB quantized keys (0 = masked)
    __shared__ unsigned hist[8][128];         // 4 KB: 256 bins packed 2/u32, per row
    __shared__ unsigned short klist[8][TOPK]; // 2 KB

    const int h = blockIdx.x;                 // gridX=16 -> linear id % 8 == h % 8: head->XCD pin
    const int q0 = blockIdx.y * 8;
    const int tid = threadIdx.x, lane = tid & 63, wv = tid >> 6;
    const int ntiles = (q0 + 8 + 63) >> 6;
    const int SB = ntiles * 64;
    const size_t hb = (size_t)h * S_LEN;

    // zero packed hist (8*128 = 1024 words)
    ((unsigned*)hist)[tid] = 0u;
    ((unsigned*)hist)[tid + 512] = 0u;

    // ---- Q fragments: rows q0..q0+7 duplicated across fr 0-7 / 8-15 ----
    const int fr = lane & 15;
    const int ak = (lane >> 4) * 8;
    const short* qp_h = (const short*)qhi + (hb + q0 + (fr & 7)) * HD;
    const short* qp_l = (const short*)qlo + (hb + q0 + (fr & 7)) * HD;
    s16x8 qa_h0 = *(const s16x8*)(qp_h + ak);
    s16x8 qa_h1 = *(const s16x8*)(qp_h + ak + 32);
    s16x8 qa_l0 = *(const s16x8*)(qp_l + ak);
    s16x8 qa_l1 = *(const s16x8*)(qp_l + ak + 32);
    __syncthreads();

    // ---- scores via MFMA (split-bf16) + quantize + fused hi-byte histogram ----
    for (int t = wv; t < ntiles; t += 8) {
        const int k0 = t * 64;
        #pragma unroll
        for (int cb = 0; cb < 4; ++cb) {
            const int key = k0 + cb * 16 + fr;
            const short* kh_ = (const short*)khi + (hb + key) * HD;
            const short* kl_ = (const short*)klo + (hb + key) * HD;
            s16x8 b_h0 = *(const s16x8*)(kh_ + ak);
            s16x8 b_h1 = *(const s16x8*)(kh_ + ak + 32);
            s16x8 b_l0 = *(const s16x8*)(kl_ + ak);
            s16x8 b_l1 = *(const s16x8*)(kl_ + ak + 32);
            f32x4 acc = {};
            acc = __builtin_amdgcn_mfma_f32_16x16x32_bf16(qa_h0, b_h0, acc, 0, 0, 0);
            acc = __builtin_amdgcn_mfma_f32_16x16x32_bf16(qa_h1, b_h1, acc, 0, 0, 0);
            acc = __builtin_amdgcn_mfma_f32_16x16x32_bf16(qa_h0, b_l0, acc, 0, 0, 0);
            acc = __builtin_amdgcn_mfma_f32_16x16x32_bf16(qa_h1, b_l1, acc, 0, 0, 0);
            acc = __builtin_amdgcn_mfma_f32_16x16x32_bf16(qa_l0, b_h0, acc, 0, 0, 0);
            acc = __builtin_amdgcn_mfma_f32_16x16x32_bf16(qa_l1, b_h1, acc, 0, 0, 0);
            #pragma unroll
            for (int j = 0; j < 4; ++j) {
                const int rowD = (lane >> 4) * 4 + j;
                if (rowD < 8) {
                    float s = acc[j] * 0.125f;
                    int ku = 0;
                    if (key <= q0 + rowD) {
                        ku = 1 + (int)((s + KOFF) * KSCALE);
                        ku = ku < 1 ? 1 : (ku > 65535 ? 65535 : ku);
                        const int hibin = ku >> 8;
                        atomicAdd(&hist[rowD][hibin >> 1], (hibin & 1) ? 0x10000u : 1u);
                    }
                    su[rowD][key] = (unsigned short)ku;
                }
            }
        }
    }
    __syncthreads();

    // ---- per-wave: row = wv ----
    const int nchT = (SB + 255) >> 8;
    const int row = wv;
    const int q = q0 + row;
    const int need = (q + 1 < TOPK) ? q + 1 : TOPK;

    if (q < TOPK) {
        for (int s = lane; s < need; s += 64) klist[row][s] = (unsigned short)s;
        for (int s = need + lane; s < TOPK; s += 64) klist[row][s] = 0;
    } else {
        // B1 from fused hi-byte histogram
        unsigned w0 = hist[row][lane * 2], w1 = hist[row][lane * 2 + 1];
        int B1, need2, eqc1;
        find_byte4(w0 & 0xffffu, w0 >> 16, w1 & 0xffffu, w1 >> 16, need, lane, B1, need2, eqc1);

        // zero own hist row, then lo-byte pass among hi==B1
        hist[row][lane * 2] = 0u; hist[row][lane * 2 + 1] = 0u;
        __asm__ volatile("s_waitcnt lgkmcnt(0)" ::: "memory");
        for (int c = 0; c < nchT; ++c) {
            const int base = (c << 8) + lane * 4;
            if (base < SB) {
                unsigned long long w8 = *(const unsigned long long*)&su[row][base];
                #pragma unroll
                for (int jj = 0; jj < 4; ++jj) {
                    unsigned kx = (unsigned)((w8 >> (16 * jj)) & 0xffffu);
                    if (kx && (kx >> 8) == (unsigned)B1) {
                        unsigned lob = kx & 255u;
                        atomicAdd(&hist[row][lob >> 1], (lob & 1) ? 0x10000u : 1u);
                    }
                }
            }
        }
        __asm__ volatile("s_waitcnt lgkmcnt(0)" ::: "memory");
        unsigned v0 = hist[row][lane * 2], v1 = hist[row][lane * 2 + 1];
        int B2, takeEq, eqc2;
        find_byte4(v0 & 0xffffu, v0 >> 16, v1 & 0xffffu, v1 >> 16, need2, lane, B2, takeEq, eqc2);

        const unsigned T = ((unsigned)B1 << 8) | (unsigned)B2;
        const int gtTot = need - takeEq;
        const bool tieEasy = (takeEq == eqc2);

        // compaction
        int gbase = 0, te = 0;
        for (int c = 0; c < nchT; ++c) {
            const int base = (c << 8) + lane * 4;
            const bool g = base < SB;
            unsigned long long w8 = g ? *(const unsigned long long*)&su[row][base] : 0ull;
            unsigned kk[4];
            kk[0] = (unsigned)(w8 & 0xffff); kk[1] = (unsigned)((w8 >> 16) & 0xffff);
            kk[2] = (unsigned)((w8 >> 32) & 0xffff); kk[3] = (unsigned)((w8 >> 48) & 0xffff);
            bool f0, f1, f2, f3;
            if (tieEasy) { f0 = kk[0] >= T; f1 = kk[1] >= T; f2 = kk[2] >= T; f3 = kk[3] >= T; }
            else         { f0 = kk[0] >  T; f1 = kk[1] >  T; f2 = kk[2] >  T; f3 = kk[3] >  T; }
            unsigned cl = (unsigned)f0 + f1 + f2 + f3;
            unsigned inc = wave_prefix_incl(cl, lane);
            int slot = gbase + (int)(inc - cl);
            if (f0) klist[row][slot++] = (unsigned short)(base + 0);
            if (f1) klist[row][slot++] = (unsigned short)(base + 1);
            if (f2) klist[row][slot++] = (unsigned short)(base + 2);
            if (f3) klist[row][slot++] = (unsigned short)(base + 3);
            gbase += (int)__shfl((int)inc, 63);
            if (!tieEasy) {
                #pragma unroll
                for (int j = 0; j < 4; ++j) {
                    bool tj = g && (kk[j] == T);
                    unsigned long long bal = __ballot(tj);
                    int r = te + (int)__popcll(bal & ((1ull << lane) - 1ull));
                    if (tj && r < takeEq) klist[row][gtTot + r] = (unsigned short)(base + j);
                    te += (int)__popcll(bal);
                }
            }
        }
    }
    __asm__ volatile("s_waitcnt lgkmcnt(0)" ::: "memory");

    // ---- PV: lane = (key-slot g=lane>>3, dim-slice d0=(lane&7)*8), bf16 V ----
    const int g = lane >> 3;
    const int d0 = (lane & 7) * 8;
    const short* vb = (const short*)vhb + hb * HD;
    float acc8[8] = {0.f, 0.f, 0.f, 0.f, 0.f, 0.f, 0.f, 0.f};
    float psum = 0.f;

    #pragma unroll
    for (int grp = 0; grp < 4; ++grp) {
        int kk[4]; float pp[4];
        #pragma unroll
        for (int b = 0; b < 4; ++b) {
            const int slot = (grp * 4 + b) * 8 + g;
            const int k = klist[row][slot];
            kk[b] = k;
            pp[b] = (slot < need) ? __expf(((float)su[row][k] - 0.5f) * KINV - KOFF) : 0.f;
        }
        s16x8 vv[4];
        #pragma unroll
        for (int b = 0; b < 4; ++b) vv[b] = *(const s16x8*)(vb + (size_t)kk[b] * HD + d0);
        #pragma unroll
        for (int b = 0; b < 4; ++b) {
            psum += pp[b];
            #pragma unroll
            for (int j = 0; j < 8; ++j) {
                unsigned short us = (unsigned short)vv[b][j];
                float vf = __bfloat162float(*reinterpret_cast<__hip_bfloat16*>(&us));
                acc8[j] += pp[b] * vf;
            }
        }
    }

    #pragma unroll
    for (int off = 8; off < 64; off <<= 1) {
        psum += __shfl_xor(psum, off);
        #pragma unroll
        for (int j = 0; j < 8; ++j) acc8[j] += __shfl_xor(acc8[j], off);
    }

    if (lane < 8) {
        const float inv = 1.0f / psum;
        s16x8 r;
        #pragma unroll
        for (int j = 0; j < 8; ++j) {
            __hip_bfloat16 bf = __float2bfloat16(acc8[j] * inv);
            r[j] = *reinterpret_cast<short*>(&bf);
        }
        *(s16x8*)((short*)yb + (size_t)q * C_DIM + h * HD + lane * 8) = r;
    }
}

// ---------------- launch ----------------
extern "C" void kernel_launch(void* const* d_in, const int* in_sizes, int n_in,
                              void* d_out, int out_size, void* d_ws, size_t ws_size,
                              hipStream_t stream)
{
    const float* x      = (const float*)d_in[0];
    const float* w_qkv  = (const float*)d_in[1];
    const float* w_proj = (const float*)d_in[2];
    float* out = (float*)d_out;

    char* ws = (char*)d_ws;
    size_t off = 0;
    auto alloc = [&](size_t bytes) -> void* {
        void* p = ws + off;
        off += (bytes + 255) & ~(size_t)255;
        return p;
    };
    __hip_bfloat16* xb  = (__hip_bfloat16*)alloc((size_t)S_LEN * C_DIM * 2);
    __hip_bfloat16* wqb = (__hip_bfloat16*)alloc((size_t)3 * C_DIM * C_DIM * 2);
    __hip_bfloat16* wpb = (__hip_bfloat16*)alloc((size_t)C_DIM * C_DIM * 2);
    float* qkvf = (float*)alloc((size_t)S_LEN * 3 * C_DIM * 4);
    __hip_bfloat16* qhi = (__hip_bfloat16*)alloc((size_t)NH * S_LEN * HD * 2);
    __hip_bfloat16* qlo = (__hip_bfloat16*)alloc((size_t)NH * S_LEN * HD * 2);
    __hip_bfloat16* khi = (__hip_bfloat16*)alloc((size_t)NH * S_LEN * HD * 2);
    __hip_bfloat16* klo = (__hip_bfloat16*)alloc((size_t)NH * S_LEN * HD * 2);
    __hip_bfloat16* vhb = (__hip_bfloat16*)alloc((size_t)NH * S_LEN * HD * 2);
    __hip_bfloat16* yb  = (__hip_bfloat16*)alloc((size_t)S_LEN * C_DIM * 2);

    int n1 = S_LEN * C_DIM, n2 = 3 * C_DIM * C_DIM, n3 = C_DIM * C_DIM;
    cvt_f32_bf16<<<n1 / 4 / 256, 256, 0, stream>>>(x, xb, n1);
    cvt_f32_bf16<<<n2 / 4 / 256, 256, 0, stream>>>(w_qkv, wqb, n2);
    cvt_f32_bf16<<<n3 / 4 / 256, 256, 0, stream>>>(w_proj, wpb, n3);

    gemm_bt<<<dim3(3 * C_DIM / 128, S_LEN / 128), 256, 0, stream>>>(xb, wqb, qkvf, S_LEN, 3 * C_DIM, C_DIM);

    rope_norm<<<NH * S_LEN / 4, 256, 0, stream>>>(qkvf, qhi, qlo, khi, klo, vhb);

    attn5<<<dim3(NH, S_LEN / 8), 512, 0, stream>>>(qhi, qlo, khi, klo, vhb, yb);

    gemm_bt<<<dim3(C_DIM / 128, S_LEN / 128), 256, 0, stream>>>(yb, wpb, out, S_LEN, C_DIM, C_DIM);
}